// Round 1
// baseline (320.888 us; speedup 1.0000x reference)
//
#include <hip/hip_runtime.h>

#define BATCH 65536
#define BN_EPS 1e-5f

// ---------------------------------------------------------------------------
// Kernel 0: precompute M[l,w] = RX(t1) @ RZ(t0) as 2x2 complex, 12 gates.
// Mbuf layout: gate g = l*4+w, 8 floats: re00,im00,re01,im01,re10,im10,re11,im11
// ez = exp(-i t0/2) = (c0, -s0); ezc = (c0, s0); cx = c1; sx = -i s1 = (0,-s1)
// M = [[cx*ez, sx*ezc],[sx*ez, cx*ezc]]
// ---------------------------------------------------------------------------
__global__ __launch_bounds__(64) void gates_kernel(const float* __restrict__ params,
                                                   float* __restrict__ Mbuf) {
    int t = threadIdx.x;
    if (t < 12) {
        float t0 = params[t * 3 + 0];
        float t1 = params[t * 3 + 1];
        float s0 = sinf(0.5f * t0), c0 = cosf(0.5f * t0);
        float s1 = sinf(0.5f * t1), c1 = cosf(0.5f * t1);
        float* m = Mbuf + t * 8;
        m[0] = c1 * c0;   m[1] = -c1 * s0;   // M00 = cx*ez
        m[2] = s1 * s0;   m[3] = -s1 * c0;   // M01 = sx*ezc
        m[4] = -s1 * s0;  m[5] = -s1 * c0;   // M10 = sx*ez
        m[6] = c1 * c0;   m[7] = c1 * s0;    // M11 = cx*ezc
    }
}

// ---------------------------------------------------------------------------
// Kernel A: encoding. One wave (64 lanes) per sample. 784 floats = 196 float4,
// each float4 lies entirely inside one 49-float4 group. Coalesced 16B/lane.
// ---------------------------------------------------------------------------
__global__ __launch_bounds__(256) void encode_kernel(const float* __restrict__ x,
                                                     float* __restrict__ enc,
                                                     int batch) {
    int wave = (int)((blockIdx.x * blockDim.x + threadIdx.x) >> 6);
    int lane = threadIdx.x & 63;
    if (wave >= batch) return;
    const float4* xs = (const float4*)(x + (size_t)wave * 784);
    float s0 = 0.f, s1 = 0.f, s2 = 0.f, s3 = 0.f;
#pragma unroll
    for (int it = 0; it < 4; it++) {
        int f = it * 64 + lane;
        if (f < 196) {
            float4 v = xs[f];
            float vs = v.x + v.y + v.z + v.w;
            int g = f / 49;
            s0 += (g == 0) ? vs : 0.0f;
            s1 += (g == 1) ? vs : 0.0f;
            s2 += (g == 2) ? vs : 0.0f;
            s3 += (g == 3) ? vs : 0.0f;
        }
    }
#pragma unroll
    for (int off = 32; off > 0; off >>= 1) {
        s0 += __shfl_down(s0, off);
        s1 += __shfl_down(s1, off);
        s2 += __shfl_down(s2, off);
        s3 += __shfl_down(s3, off);
    }
    if (lane == 0) {
        const float inv = 1.0f / 196.0f;
        ((float4*)enc)[wave] = make_float4(s0 * inv, s1 * inv, s2 * inv, s3 * inv);
    }
}

// ---------------------------------------------------------------------------
// Kernel B: statevector sim, one thread per sample. 16 complex amps in regs.
// Wire w <-> bit with stride 8>>w (state index i = b0*8+b1*4+b2*2+b3).
// Also computes out = z @ W^T + b, stores it, and accumulates sum/sumsq.
// ---------------------------------------------------------------------------
__global__ __launch_bounds__(256) void sim_kernel(const float* __restrict__ enc,
                                                  const float* __restrict__ Mbuf,
                                                  const float* __restrict__ Wm,
                                                  const float* __restrict__ bvec,
                                                  float* __restrict__ out_ws,
                                                  float* __restrict__ sums) {
    int t = blockIdx.x * blockDim.x + threadIdx.x;
    float4 e = ((const float4*)enc)[t];
    float ang[4] = {e.x, e.y, e.z, e.w};
    float cw[4], sw[4];
#pragma unroll
    for (int w = 0; w < 4; w++) {
        __sincosf(0.5f * ang[w], &sw[w], &cw[w]);
    }

    float sr[16], si[16];
#pragma unroll
    for (int i = 0; i < 16; i++) { sr[i] = 0.f; si[i] = 0.f; }
    sr[0] = 1.0f;

#pragma unroll
    for (int l = 0; l < 3; l++) {
#pragma unroll
        for (int w = 0; w < 4; w++) {
            const float* m = Mbuf + (l * 4 + w) * 8;
            float c = cw[w], s = sw[w];
            // U = M @ RY:  RY = [[c,-s],[s,c]]
            float u00r = m[0] * c + m[2] * s;
            float u00i = m[1] * c + m[3] * s;
            float u01r = -m[0] * s + m[2] * c;
            float u01i = -m[1] * s + m[3] * c;
            float u10r = m[4] * c + m[6] * s;
            float u10i = m[5] * c + m[7] * s;
            float u11r = -m[4] * s + m[6] * c;
            float u11i = -m[5] * s + m[7] * c;
            const int stride = 8 >> w;
#pragma unroll
            for (int i = 0; i < 16; i++) {
                if (i & stride) continue;  // bit_w == 0 only
                int j = i | stride;
                float a0r = sr[i], a0i = si[i];
                float a1r = sr[j], a1i = si[j];
                sr[i] = u00r * a0r - u00i * a0i + u01r * a1r - u01i * a1i;
                si[i] = u00r * a0i + u00i * a0r + u01r * a1i + u01i * a1r;
                sr[j] = u10r * a0r - u10i * a0i + u11r * a1r - u11i * a1i;
                si[j] = u10r * a0i + u10i * a0r + u11r * a1i + u11i * a1r;
            }
            if (w < 3) {  // CNOT(control=w, target=w+1)
                const int ts = 8 >> (w + 1);
#pragma unroll
                for (int i = 0; i < 16; i++) {
                    if (!(i & stride)) continue;  // control == 1
                    if (i & ts) continue;         // target == 0 (pair base)
                    int j = i | ts;
                    float tr = sr[i]; sr[i] = sr[j]; sr[j] = tr;
                    float ti = si[i]; si[i] = si[j]; si[j] = ti;
                }
            }
        }
    }

    float p[16];
#pragma unroll
    for (int i = 0; i < 16; i++) p[i] = sr[i] * sr[i] + si[i] * si[i];
    float z[4];
#pragma unroll
    for (int w = 0; w < 4; w++) {
        const int stride = 8 >> w;
        float acc = 0.f;
#pragma unroll
        for (int i = 0; i < 16; i++) acc += (i & stride) ? -p[i] : p[i];
        z[w] = acc;
    }

    float o[4];
#pragma unroll
    for (int j = 0; j < 4; j++) {
        o[j] = bvec[j] + Wm[j * 4 + 0] * z[0] + Wm[j * 4 + 1] * z[1] +
               Wm[j * 4 + 2] * z[2] + Wm[j * 4 + 3] * z[3];
    }
    ((float4*)out_ws)[t] = make_float4(o[0], o[1], o[2], o[3]);

    // ---- block reduction of sum / sumsq (8 values) ----
    float vals[8];
#pragma unroll
    for (int j = 0; j < 4; j++) { vals[j] = o[j]; vals[4 + j] = o[j] * o[j]; }
#pragma unroll
    for (int k = 0; k < 8; k++) {
#pragma unroll
        for (int off = 32; off > 0; off >>= 1) vals[k] += __shfl_down(vals[k], off);
    }
    __shared__ float part[4][8];
    int lane = threadIdx.x & 63;
    int wv = threadIdx.x >> 6;
    if (lane == 0) {
#pragma unroll
        for (int k = 0; k < 8; k++) part[wv][k] = vals[k];
    }
    __syncthreads();
    if (threadIdx.x == 0) {
#pragma unroll
        for (int k = 0; k < 8; k++) {
            float tsum = part[0][k] + part[1][k] + part[2][k] + part[3][k];
            atomicAdd(&sums[k], tsum);
        }
    }
}

// ---------------------------------------------------------------------------
// Kernel C: BN finalize -> scale/shift per feature.
// ---------------------------------------------------------------------------
__global__ __launch_bounds__(64) void bn_finalize_kernel(const float* __restrict__ sums,
                                                         const float* __restrict__ bn_w,
                                                         const float* __restrict__ bn_b,
                                                         float* __restrict__ scsh,
                                                         float inv_batch) {
    int j = threadIdx.x;
    if (j < 4) {
        float mu = sums[j] * inv_batch;
        float ex2 = sums[4 + j] * inv_batch;
        float var = ex2 - mu * mu;
        float sc = bn_w[j] * rsqrtf(var + BN_EPS);
        scsh[j] = sc;
        scsh[4 + j] = bn_b[j] - mu * sc;
    }
}

// ---------------------------------------------------------------------------
// Kernel D: apply BN. One thread per sample (float4 in/out).
// ---------------------------------------------------------------------------
__global__ __launch_bounds__(256) void norm_kernel(const float* __restrict__ out_ws,
                                                   const float* __restrict__ scsh,
                                                   float* __restrict__ dout) {
    int t = blockIdx.x * blockDim.x + threadIdx.x;
    float4 o = ((const float4*)out_ws)[t];
    float4 sc = ((const float4*)scsh)[0];
    float4 sh = ((const float4*)scsh)[1];
    ((float4*)dout)[t] = make_float4(o.x * sc.x + sh.x, o.y * sc.y + sh.y,
                                     o.z * sc.z + sh.z, o.w * sc.w + sh.w);
}

extern "C" void kernel_launch(void* const* d_in, const int* in_sizes, int n_in,
                              void* d_out, int out_size, void* d_ws, size_t ws_size,
                              hipStream_t stream) {
    const float* x      = (const float*)d_in[0];  // (B,1,28,28)
    const float* params = (const float*)d_in[1];  // (3,4,3)
    const float* Wm     = (const float*)d_in[2];  // (4,4)
    const float* bvec   = (const float*)d_in[3];  // (4,)
    const float* bn_w   = (const float*)d_in[4];  // (4,)
    const float* bn_b   = (const float*)d_in[5];  // (4,)
    float* dout = (float*)d_out;

    const int B = in_sizes[0] / 784;  // 65536

    float* ws   = (float*)d_ws;
    float* Mbuf = ws;            // 96 floats
    float* sums = ws + 96;       // 8 floats
    float* scsh = ws + 104;      // 8 floats
    float* enc  = ws + 128;      // B*4 floats (16B aligned)
    float* outw = ws + 128 + 4 * (size_t)B;  // B*4 floats

    gates_kernel<<<1, 64, 0, stream>>>(params, Mbuf);
    hipMemsetAsync(sums, 0, 8 * sizeof(float), stream);
    // one wave per sample: B waves = B/4 blocks of 256
    encode_kernel<<<(B + 3) / 4, 256, 0, stream>>>(x, enc, B);
    sim_kernel<<<B / 256, 256, 0, stream>>>(enc, Mbuf, Wm, bvec, outw, sums);
    bn_finalize_kernel<<<1, 64, 0, stream>>>(sums, bn_w, bn_b, scsh, 1.0f / (float)B);
    norm_kernel<<<B / 256, 256, 0, stream>>>(outw, scsh, dout);
}

// Round 2
// 319.140 us; speedup vs baseline: 1.0055x; 1.0055x over previous
//
#include <hip/hip_runtime.h>

#define BN_EPS 1e-5f

// ---------------------------------------------------------------------------
// Kernel A: encoding. One wave (64 lanes) per sample. 784 floats = 196 float4.
// Group g = f/49 boundaries: iter0 f=0..63 (g0|g1 @49), iter1 64..127 (g1|g2 @98),
// iter2 128..191 (g2|g3 @147), iter3 f=192..195 lanes 0..3 (g3).
// ---------------------------------------------------------------------------
__global__ __launch_bounds__(256) void encode_kernel(const float* __restrict__ x,
                                                     float* __restrict__ enc) {
    int wave = (int)((blockIdx.x * blockDim.x + threadIdx.x) >> 6);
    int lane = threadIdx.x & 63;
    const float4* xs = (const float4*)(x + (size_t)wave * 784);

    float4 v0 = xs[lane];
    float4 v1 = xs[64 + lane];
    float4 v2 = xs[128 + lane];
    float4 v3 = (lane < 4) ? xs[192 + lane] : make_float4(0.f, 0.f, 0.f, 0.f);

    float t0 = (v0.x + v0.y) + (v0.z + v0.w);
    float t1 = (v1.x + v1.y) + (v1.z + v1.w);
    float t2 = (v2.x + v2.y) + (v2.z + v2.w);
    float t3 = (v3.x + v3.y) + (v3.z + v3.w);

    float s0 = (lane < 49) ? t0 : 0.f;
    float s1 = ((lane >= 49) ? t0 : 0.f) + ((lane < 34) ? t1 : 0.f);
    float s2 = ((lane >= 34) ? t1 : 0.f) + ((lane < 19) ? t2 : 0.f);
    float s3 = ((lane >= 19) ? t2 : 0.f) + t3;

#pragma unroll
    for (int off = 32; off > 0; off >>= 1) {
        s0 += __shfl_down(s0, off);
        s1 += __shfl_down(s1, off);
        s2 += __shfl_down(s2, off);
        s3 += __shfl_down(s3, off);
    }
    if (lane == 0) {
        const float inv = 1.0f / 196.0f;
        ((float4*)enc)[wave] = make_float4(s0 * inv, s1 * inv, s2 * inv, s3 * inv);
    }
}

// ---------------------------------------------------------------------------
// Kernel B: statevector sim, one thread per sample. Gate matrices
// M[l,w] = RX(t1)@RZ(t0) computed per-block into LDS (12 gates x 8 floats).
// Wire w <-> bit with stride 8>>w. Also out = z@W^T+b, stored to ws, plus
// block-reduced sum/sumsq atomics for BN.
// ---------------------------------------------------------------------------
__global__ __launch_bounds__(256) void sim_kernel(const float* __restrict__ enc,
                                                  const float* __restrict__ params,
                                                  const float* __restrict__ Wm,
                                                  const float* __restrict__ bvec,
                                                  float* __restrict__ out_ws,
                                                  float* __restrict__ sums) {
    __shared__ float G[96];    // 12 gates x 8 floats
    __shared__ float WB[20];   // W (16, row-major) + b (4)
    if (threadIdx.x < 12) {
        int t = threadIdx.x;
        float t0 = params[t * 3 + 0];
        float t1 = params[t * 3 + 1];
        float s0, c0, s1, c1;
        __sincosf(0.5f * t0, &s0, &c0);
        __sincosf(0.5f * t1, &s1, &c1);
        float* m = G + t * 8;
        m[0] = c1 * c0;   m[1] = -c1 * s0;   // M00 = cx*ez
        m[2] = s1 * s0;   m[3] = -s1 * c0;   // M01 = sx*ezc
        m[4] = -s1 * s0;  m[5] = -s1 * c0;   // M10 = sx*ez
        m[6] = c1 * c0;   m[7] = c1 * s0;    // M11 = cx*ezc
    } else if (threadIdx.x < 32) {
        int k = threadIdx.x - 12;
        if (k < 16) WB[k] = Wm[k];
        else WB[k] = bvec[k - 16];
    }
    __syncthreads();

    int t = blockIdx.x * blockDim.x + threadIdx.x;
    float4 e = ((const float4*)enc)[t];
    float ang[4] = {e.x, e.y, e.z, e.w};
    float cw[4], sw[4];
#pragma unroll
    for (int w = 0; w < 4; w++) __sincosf(0.5f * ang[w], &sw[w], &cw[w]);

    float sr[16], si[16];
#pragma unroll
    for (int i = 0; i < 16; i++) { sr[i] = 0.f; si[i] = 0.f; }
    sr[0] = 1.0f;

#pragma unroll
    for (int l = 0; l < 3; l++) {
#pragma unroll
        for (int w = 0; w < 4; w++) {
            const float* m = G + (l * 4 + w) * 8;
            float c = cw[w], s = sw[w];
            // U = M @ RY, RY = [[c,-s],[s,c]]
            float u00r = m[0] * c + m[2] * s;
            float u00i = m[1] * c + m[3] * s;
            float u01r = -m[0] * s + m[2] * c;
            float u01i = -m[1] * s + m[3] * c;
            float u10r = m[4] * c + m[6] * s;
            float u10i = m[5] * c + m[7] * s;
            float u11r = -m[4] * s + m[6] * c;
            float u11i = -m[5] * s + m[7] * c;
            const int stride = 8 >> w;
#pragma unroll
            for (int i = 0; i < 16; i++) {
                if (i & stride) continue;
                int j = i | stride;
                float a0r = sr[i], a0i = si[i];
                float a1r = sr[j], a1i = si[j];
                sr[i] = u00r * a0r - u00i * a0i + u01r * a1r - u01i * a1i;
                si[i] = u00r * a0i + u00i * a0r + u01r * a1i + u01i * a1r;
                sr[j] = u10r * a0r - u10i * a0i + u11r * a1r - u11i * a1i;
                si[j] = u10r * a0i + u10i * a0r + u11r * a1i + u11i * a1r;
            }
            if (w < 3) {  // CNOT(control=w, target=w+1)
                const int ts = 8 >> (w + 1);
#pragma unroll
                for (int i = 0; i < 16; i++) {
                    if (!(i & stride)) continue;
                    if (i & ts) continue;
                    int j = i | ts;
                    float tr = sr[i]; sr[i] = sr[j]; sr[j] = tr;
                    float ti = si[i]; si[i] = si[j]; si[j] = ti;
                }
            }
        }
    }

    float p[16];
#pragma unroll
    for (int i = 0; i < 16; i++) p[i] = sr[i] * sr[i] + si[i] * si[i];
    float z[4];
#pragma unroll
    for (int w = 0; w < 4; w++) {
        const int stride = 8 >> w;
        float acc = 0.f;
#pragma unroll
        for (int i = 0; i < 16; i++) acc += (i & stride) ? -p[i] : p[i];
        z[w] = acc;
    }

    float o[4];
#pragma unroll
    for (int j = 0; j < 4; j++) {
        o[j] = WB[16 + j] + WB[j * 4 + 0] * z[0] + WB[j * 4 + 1] * z[1] +
               WB[j * 4 + 2] * z[2] + WB[j * 4 + 3] * z[3];
    }
    ((float4*)out_ws)[t] = make_float4(o[0], o[1], o[2], o[3]);

    // block reduction of sum / sumsq
    float vals[8];
#pragma unroll
    for (int j = 0; j < 4; j++) { vals[j] = o[j]; vals[4 + j] = o[j] * o[j]; }
#pragma unroll
    for (int k = 0; k < 8; k++) {
#pragma unroll
        for (int off = 32; off > 0; off >>= 1) vals[k] += __shfl_down(vals[k], off);
    }
    __shared__ float part[4][8];
    int lane = threadIdx.x & 63;
    int wv = threadIdx.x >> 6;
    if (lane == 0) {
#pragma unroll
        for (int k = 0; k < 8; k++) part[wv][k] = vals[k];
    }
    __syncthreads();
    if (threadIdx.x == 0) {
#pragma unroll
        for (int k = 0; k < 8; k++) {
            float tsum = part[0][k] + part[1][k] + part[2][k] + part[3][k];
            atomicAdd(&sums[k], tsum);
        }
    }
}

// ---------------------------------------------------------------------------
// Kernel C: BN finalize (in-block) + apply. One thread per sample.
// ---------------------------------------------------------------------------
__global__ __launch_bounds__(256) void norm_kernel(const float* __restrict__ out_ws,
                                                   const float* __restrict__ sums,
                                                   const float* __restrict__ bn_w,
                                                   const float* __restrict__ bn_b,
                                                   float* __restrict__ dout,
                                                   float inv_batch) {
    __shared__ float sc[4], sh[4];
    if (threadIdx.x < 4) {
        int j = threadIdx.x;
        float mu = sums[j] * inv_batch;
        float ex2 = sums[4 + j] * inv_batch;
        float var = ex2 - mu * mu;
        float s = bn_w[j] * rsqrtf(var + BN_EPS);
        sc[j] = s;
        sh[j] = bn_b[j] - mu * s;
    }
    __syncthreads();
    int t = blockIdx.x * blockDim.x + threadIdx.x;
    float4 o = ((const float4*)out_ws)[t];
    ((float4*)dout)[t] = make_float4(o.x * sc[0] + sh[0], o.y * sc[1] + sh[1],
                                     o.z * sc[2] + sh[2], o.w * sc[3] + sh[3]);
}

extern "C" void kernel_launch(void* const* d_in, const int* in_sizes, int n_in,
                              void* d_out, int out_size, void* d_ws, size_t ws_size,
                              hipStream_t stream) {
    const float* x      = (const float*)d_in[0];  // (B,1,28,28)
    const float* params = (const float*)d_in[1];  // (3,4,3)
    const float* Wm     = (const float*)d_in[2];  // (4,4)
    const float* bvec   = (const float*)d_in[3];  // (4,)
    const float* bn_w   = (const float*)d_in[4];  // (4,)
    const float* bn_b   = (const float*)d_in[5];  // (4,)
    float* dout = (float*)d_out;

    const int B = in_sizes[0] / 784;  // 65536

    float* ws   = (float*)d_ws;
    float* sums = ws;                       // 8 floats
    float* enc  = ws + 64;                  // B*4 floats (256B-aligned)
    float* outw = ws + 64 + 4 * (size_t)B;  // B*4 floats

    hipMemsetAsync(sums, 0, 8 * sizeof(float), stream);
    encode_kernel<<<B / 4, 256, 0, stream>>>(x, enc);
    sim_kernel<<<B / 256, 256, 0, stream>>>(enc, params, Wm, bvec, outw, sums);
    norm_kernel<<<B / 256, 256, 0, stream>>>(outw, sums, bn_w, bn_b, dout, 1.0f / (float)B);
}

// Round 4
// 298.030 us; speedup vs baseline: 1.0767x; 1.0708x over previous
//
#include <hip/hip_runtime.h>

#define BN_EPS 1e-5f
#define NBLK 1024   // kernel-1 blocks; each owns 64 samples

// ---------------------------------------------------------------------------
// Kernel 1: fused encode + sim + linear + per-block BN partials.
// Block b owns samples [b*64, b*64+64):
//   phase 1: 4 waves encode 16 samples each (coalesced float4) -> LDS
//   phase 2: lanes of wave 0 sim one sample each, out -> global ws,
//            wave-reduced sum/sumsq -> partials[b][8]  (no atomics)
// ---------------------------------------------------------------------------
__global__ __launch_bounds__(256) void encode_sim_kernel(
    const float* __restrict__ x,
    const float* __restrict__ params,
    const float* __restrict__ Wm,
    const float* __restrict__ bvec,
    float* __restrict__ out_ws,
    float* __restrict__ partials) {
    __shared__ float G[96];        // 12 gates x 8 floats
    __shared__ float encl[64][5];  // stride 5 -> conflict-free

    const int tid  = threadIdx.x;
    const int lane = tid & 63;
    const int wv   = tid >> 6;
    const int b    = blockIdx.x;
    const int base = b * 64;

    // gates: M[l,w] = RX(t1) @ RZ(t0)
    if (tid < 12) {
        float t0 = params[tid * 3 + 0];
        float t1 = params[tid * 3 + 1];
        float s0, c0, s1, c1;
        __sincosf(0.5f * t0, &s0, &c0);
        __sincosf(0.5f * t1, &s1, &c1);
        float* m = G + tid * 8;
        m[0] = c1 * c0;   m[1] = -c1 * s0;   // M00 = cx*ez
        m[2] = s1 * s0;   m[3] = -s1 * c0;   // M01 = sx*ezc
        m[4] = -s1 * s0;  m[5] = -s1 * c0;   // M10 = sx*ez
        m[6] = c1 * c0;   m[7] = c1 * s0;    // M11 = cx*ezc
    }

    // ---- phase 1: encode (4 waves x 16 samples) ----
#pragma unroll 2
    for (int i = 0; i < 16; i++) {
        int sl = wv * 16 + i;
        const float4* xs = (const float4*)(x + (size_t)(base + sl) * 784);
        float4 v0 = xs[lane];
        float4 v1 = xs[64 + lane];
        float4 v2 = xs[128 + lane];
        float4 v3 = (lane < 4) ? xs[192 + lane] : make_float4(0.f, 0.f, 0.f, 0.f);

        float t0 = (v0.x + v0.y) + (v0.z + v0.w);
        float t1 = (v1.x + v1.y) + (v1.z + v1.w);
        float t2 = (v2.x + v2.y) + (v2.z + v2.w);
        float t3 = (v3.x + v3.y) + (v3.z + v3.w);

        // group g = f/49 boundaries at 49, 98, 147
        float s0 = (lane < 49) ? t0 : 0.f;
        float s1 = ((lane >= 49) ? t0 : 0.f) + ((lane < 34) ? t1 : 0.f);
        float s2 = ((lane >= 34) ? t1 : 0.f) + ((lane < 19) ? t2 : 0.f);
        float s3 = ((lane >= 19) ? t2 : 0.f) + t3;

#pragma unroll
        for (int off = 32; off > 0; off >>= 1) {
            s0 += __shfl_down(s0, off);
            s1 += __shfl_down(s1, off);
            s2 += __shfl_down(s2, off);
            s3 += __shfl_down(s3, off);
        }
        if (lane == 0) {
            const float inv = 1.0f / 196.0f;
            encl[sl][0] = s0 * inv;
            encl[sl][1] = s1 * inv;
            encl[sl][2] = s2 * inv;
            encl[sl][3] = s3 * inv;
        }
    }
    __syncthreads();

    // ---- phase 2: sim (wave 0 only, one sample per lane) ----
    if (wv == 0) {
        float ang[4] = {encl[lane][0], encl[lane][1], encl[lane][2], encl[lane][3]};
        float cw[4], sw[4];
#pragma unroll
        for (int w = 0; w < 4; w++) __sincosf(0.5f * ang[w], &sw[w], &cw[w]);

        float sr[16], si[16];
#pragma unroll
        for (int i = 0; i < 16; i++) { sr[i] = 0.f; si[i] = 0.f; }
        sr[0] = 1.0f;

#pragma unroll
        for (int l = 0; l < 3; l++) {
#pragma unroll
            for (int w = 0; w < 4; w++) {
                const float* m = G + (l * 4 + w) * 8;
                float c = cw[w], s = sw[w];
                // U = M @ RY, RY = [[c,-s],[s,c]]
                float u00r = m[0] * c + m[2] * s;
                float u00i = m[1] * c + m[3] * s;
                float u01r = -m[0] * s + m[2] * c;
                float u01i = -m[1] * s + m[3] * c;
                float u10r = m[4] * c + m[6] * s;
                float u10i = m[5] * c + m[7] * s;
                float u11r = -m[4] * s + m[6] * c;
                float u11i = -m[5] * s + m[7] * c;
                const int stride = 8 >> w;
#pragma unroll
                for (int i = 0; i < 16; i++) {
                    if (i & stride) continue;
                    int j = i | stride;
                    float a0r = sr[i], a0i = si[i];
                    float a1r = sr[j], a1i = si[j];
                    sr[i] = u00r * a0r - u00i * a0i + u01r * a1r - u01i * a1i;
                    si[i] = u00r * a0i + u00i * a0r + u01r * a1i + u01i * a1r;
                    sr[j] = u10r * a0r - u10i * a0i + u11r * a1r - u11i * a1i;
                    si[j] = u10r * a0i + u10i * a0r + u11r * a1i + u11i * a1r;
                }
                if (w < 3) {  // CNOT(control=w, target=w+1)
                    const int ts = 8 >> (w + 1);
#pragma unroll
                    for (int i = 0; i < 16; i++) {
                        if (!(i & stride)) continue;
                        if (i & ts) continue;
                        int j = i | ts;
                        float tr = sr[i]; sr[i] = sr[j]; sr[j] = tr;
                        float ti = si[i]; si[i] = si[j]; si[j] = ti;
                    }
                }
            }
        }

        float p[16];
#pragma unroll
        for (int i = 0; i < 16; i++) p[i] = sr[i] * sr[i] + si[i] * si[i];
        float z[4];
#pragma unroll
        for (int w = 0; w < 4; w++) {
            const int stride = 8 >> w;
            float acc = 0.f;
#pragma unroll
            for (int i = 0; i < 16; i++) acc += (i & stride) ? -p[i] : p[i];
            z[w] = acc;
        }

        float o[4];
#pragma unroll
        for (int j = 0; j < 4; j++) {
            o[j] = bvec[j] + Wm[j * 4 + 0] * z[0] + Wm[j * 4 + 1] * z[1] +
                   Wm[j * 4 + 2] * z[2] + Wm[j * 4 + 3] * z[3];
        }
        ((float4*)out_ws)[base + lane] = make_float4(o[0], o[1], o[2], o[3]);

        // per-block BN partials (8 values) via wave reduce, no atomics
        float vals[8];
#pragma unroll
        for (int j = 0; j < 4; j++) { vals[j] = o[j]; vals[4 + j] = o[j] * o[j]; }
#pragma unroll
        for (int k = 0; k < 8; k++) {
#pragma unroll
            for (int off = 32; off > 0; off >>= 1) vals[k] += __shfl_down(vals[k], off);
        }
        if (lane == 0) {
#pragma unroll
            for (int k = 0; k < 8; k++) partials[b * 8 + k] = vals[k];
        }
    }
}

// ---------------------------------------------------------------------------
// Kernel 2: reduce partials[NBLK][8] (every block, L2-resident), BN finalize,
// normalize. One thread per sample.
// ---------------------------------------------------------------------------
__global__ __launch_bounds__(256) void norm_kernel(
    const float* __restrict__ out_ws,
    const float* __restrict__ partials,
    const float* __restrict__ bn_w,
    const float* __restrict__ bn_b,
    float* __restrict__ dout,
    float inv_batch) {
    __shared__ float red[32][8];
    __shared__ float scsh[8];
    const int tid = threadIdx.x;

    {
        int f = tid & 7, row = tid >> 3;  // 32 rows x 8 features
        float acc = 0.f;
#pragma unroll 4
        for (int i = 0; i < NBLK / 32; i++) acc += partials[(row + 32 * i) * 8 + f];
        red[row][f] = acc;
    }
    __syncthreads();
    if (tid < 8) {
        float t = 0.f;
#pragma unroll
        for (int r = 0; r < 32; r++) t += red[r][tid];
        // finalize directly (8 threads; first 4 compute scale, last 4 need mu of
        // their feature too) — do it in two steps via shared
        red[0][tid] = t;  // sums8
    }
    __syncthreads();
    if (tid < 4) {
        float mu = red[0][tid] * inv_batch;
        float ex2 = red[0][tid + 4] * inv_batch;
        float var = ex2 - mu * mu;
        float s = bn_w[tid] * rsqrtf(var + BN_EPS);
        scsh[tid] = s;
        scsh[4 + tid] = bn_b[tid] - mu * s;
    }
    __syncthreads();

    int t = blockIdx.x * blockDim.x + tid;
    float4 o = ((const float4*)out_ws)[t];
    ((float4*)dout)[t] = make_float4(o.x * scsh[0] + scsh[4],
                                     o.y * scsh[1] + scsh[5],
                                     o.z * scsh[2] + scsh[6],
                                     o.w * scsh[3] + scsh[7]);
}

extern "C" void kernel_launch(void* const* d_in, const int* in_sizes, int n_in,
                              void* d_out, int out_size, void* d_ws, size_t ws_size,
                              hipStream_t stream) {
    const float* x      = (const float*)d_in[0];  // (B,1,28,28)
    const float* params = (const float*)d_in[1];  // (3,4,3)
    const float* Wm     = (const float*)d_in[2];  // (4,4)
    const float* bvec   = (const float*)d_in[3];  // (4,)
    const float* bn_w   = (const float*)d_in[4];  // (4,)
    const float* bn_b   = (const float*)d_in[5];  // (4,)
    float* dout = (float*)d_out;

    const int B = in_sizes[0] / 784;  // 65536

    float* ws       = (float*)d_ws;
    float* partials = ws;                    // NBLK*8 floats
    float* outw     = ws + NBLK * 8;         // B*4 floats (32KB-aligned)

    encode_sim_kernel<<<NBLK, 256, 0, stream>>>(x, params, Wm, bvec, outw, partials);
    norm_kernel<<<B / 256, 256, 0, stream>>>(outw, partials, bn_w, bn_b, dout,
                                             1.0f / (float)B);
}